// Round 1
// baseline (299.272 us; speedup 1.0000x reference)
//
#include <hip/hip_runtime.h>
#include <hip/hip_bf16.h>
#include <stdint.h>

typedef unsigned short ushort_t;
typedef __attribute__((ext_vector_type(8))) short bf16x8;   // 8 bf16 in 4 VGPRs (guide §3)
typedef __attribute__((ext_vector_type(4))) float f32x4;

#define BB 4
#define SS 2048
#define DD 1024
#define HDIM 1024
#define NH 16
#define DF 64
#define WWIN 16

__device__ __forceinline__ ushort_t f2bf(float f) {
    uint32_t u = __float_as_uint(f);
    u = (u + 0x7FFFu + ((u >> 16) & 1u)) >> 16;   // RNE
    return (ushort_t)u;
}
__device__ __forceinline__ float bf2f(ushort_t h) {
    return __uint_as_float(((uint32_t)h) << 16);
}

__device__ __forceinline__ void gld_lds16(const void* g, void* l) {
    __builtin_amdgcn_global_load_lds(
        (const __attribute__((address_space(1))) void*)g,
        (__attribute__((address_space(3))) void*)l, 16, 0, 0);
}

// ---------------- fp32 -> bf16 convert ----------------
__global__ void cvt_kernel(const float* __restrict__ src, ushort_t* __restrict__ dst, int n4) {
    int i = blockIdx.x * blockDim.x + threadIdx.x;
    int st = gridDim.x * blockDim.x;
    for (; i < n4; i += st) {
        float4 v = ((const float4*)src)[i];
        ushort4 o;
        o.x = f2bf(v.x); o.y = f2bf(v.y); o.z = f2bf(v.z); o.w = f2bf(v.w);
        ((ushort4*)dst)[i] = o;
    }
}

// ---------------- fused QKV GEMM ----------------
// A  = xb   (M=8192, K=1024) bf16 row-major
// Bw = Wb[z] (N=1024, K=1024) bf16 row-major  (W is (HD,D) = (N,K): out = x @ W^T)
// Out[z] = bf16(A @ Bw^T + bias)
__global__ __launch_bounds__(256) void gemm_qkv(
    const ushort_t* __restrict__ Aall,
    const ushort_t* __restrict__ Wall,
    const float* __restrict__ bq, const float* __restrict__ bk, const float* __restrict__ bv,
    ushort_t* __restrict__ Obase)
{
    const int z = blockIdx.z;
    const ushort_t* Bw = Wall + (size_t)z * 1024 * 1024;
    const float* bias = (z == 0) ? bq : ((z == 1) ? bk : bv);
    ushort_t* Out = Obase + (size_t)z * 8192 * 1024;

    const int m0 = blockIdx.x * 128;
    const int n0 = blockIdx.y * 128;
    const int K = 1024;

    __shared__ ushort_t As[128 * 32];
    __shared__ ushort_t Bs[128 * 32];

    const int t = threadIdx.x;
    const int wave = t >> 6, lane = t & 63;
    const int wm = wave >> 1, wn = wave & 1;       // 2x2 wave grid, 64x64 per wave
    const int frow = lane & 15;
    const int kcol = (lane >> 4) * 8;

    f32x4 acc[4][4] = {};

    for (int k0 = 0; k0 < K; k0 += 32) {
#pragma unroll
        for (int j = 0; j < 2; ++j) {
            int e = (j * 256 + t) * 8;             // element index in 128x32 tile
            int row = e >> 5, col = e & 31;
            gld_lds16(Aall + (size_t)(m0 + row) * K + k0 + col,
                      As + (size_t)(j * 256 + wave * 64) * 8);
            gld_lds16(Bw + (size_t)(n0 + row) * K + k0 + col,
                      Bs + (size_t)(j * 256 + wave * 64) * 8);
        }
        __syncthreads();

        bf16x8 af[4], bfr[4];
#pragma unroll
        for (int i = 0; i < 4; ++i) {
            af[i]  = *(const bf16x8*)(As + (wm * 64 + i * 16 + frow) * 32 + kcol);
            bfr[i] = *(const bf16x8*)(Bs + (wn * 64 + i * 16 + frow) * 32 + kcol);
        }
#pragma unroll
        for (int i = 0; i < 4; ++i)
#pragma unroll
            for (int j = 0; j < 4; ++j)
                acc[i][j] = __builtin_amdgcn_mfma_f32_16x16x32_bf16(af[i], bfr[j], acc[i][j], 0, 0, 0);
        __syncthreads();
    }

    const int orow0 = m0 + wm * 64;
    const int ocol0 = n0 + wn * 64;
#pragma unroll
    for (int j = 0; j < 4; ++j) {
        int col = ocol0 + j * 16 + frow;
        float bsv = bias[col];
#pragma unroll
        for (int i = 0; i < 4; ++i) {
#pragma unroll
            for (int rg = 0; rg < 4; ++rg) {
                int row = orow0 + i * 16 + (lane >> 4) * 4 + rg;
                Out[(size_t)row * 1024 + col] = f2bf(acc[i][j][rg] + bsv);
            }
        }
    }
}

// ---------------- attention (chunked-window softmax) ----------------
// wave per (b,s,h); lane = df in [0,64)
__global__ __launch_bounds__(256) void attn_kernel(
    const ushort_t* __restrict__ Qb, const ushort_t* __restrict__ Kb, const ushort_t* __restrict__ Vb,
    const float* __restrict__ bk, const float* __restrict__ bv, float* __restrict__ out)
{
    const int wave = threadIdx.x >> 6, lane = threadIdx.x & 63;
    const int wg = blockIdx.x * 4 + wave;
    const int h = wg & 15;
    const int sb = wg >> 4;
    const int s = sb & (SS - 1);
    const int b = sb >> 11;
    const int r = s + h - (WWIN - 1);
    const bool pad = (r < 0);
    const int rc = pad ? 0 : r;

    const size_t qoff = ((size_t)(b * SS + s)) * HDIM + h * DF;
    const float q = bf2f(Qb[qoff + lane]) * 0.125f;   // 1/sqrt(64)

    const ushort_t* krow = Kb + ((size_t)(b * SS + rc)) * HDIM;
    const ushort_t* vrow = Vb + ((size_t)(b * SS + rc)) * HDIM;

    float e[16];
    float mx = -1e30f;
#pragma unroll
    for (int w = 0; w < 16; ++w) {
        float kv = pad ? bk[w * 64 + lane] : bf2f(krow[w * 64 + lane]);
        float p = q * kv;
#pragma unroll
        for (int d = 1; d < 64; d <<= 1) p += __shfl_xor(p, d);
        e[w] = p;
        mx = fmaxf(mx, p);
    }
    float sum = 0.f;
#pragma unroll
    for (int w = 0; w < 16; ++w) { e[w] = __expf(e[w] - mx); sum += e[w]; }
    const float inv = 1.0f / sum;

    float acc = 0.f;
#pragma unroll
    for (int w = 0; w < 16; ++w) {
        float vv = pad ? bv[w * 64 + lane] : bf2f(vrow[w * 64 + lane]);
        acc += e[w] * vv;
    }
    out[qoff + lane] = acc * inv;
}

extern "C" void kernel_launch(void* const* d_in, const int* in_sizes, int n_in,
                              void* d_out, int out_size, void* d_ws, size_t ws_size,
                              hipStream_t stream) {
    const float* x  = (const float*)d_in[0];
    const float* Wq = (const float*)d_in[1];
    const float* bq = (const float*)d_in[2];
    const float* Wk = (const float*)d_in[3];
    const float* bk = (const float*)d_in[4];
    const float* Wv = (const float*)d_in[5];
    const float* bv = (const float*)d_in[6];
    float* out = (float*)d_out;

    ushort_t* xb  = (ushort_t*)d_ws;                       // 8192*1024 bf16
    ushort_t* Wb  = xb + (size_t)8192 * 1024;              // 3 * 1024*1024 bf16
    ushort_t* QKV = Wb + (size_t)3 * 1024 * 1024;          // 3 * 8192*1024 bf16
    ushort_t* Qb  = QKV;
    ushort_t* Kb  = QKV + (size_t)8192 * 1024;
    ushort_t* Vb  = QKV + (size_t)2 * 8192 * 1024;

    cvt_kernel<<<2048, 256, 0, stream>>>(x,  xb, 8192 * 1024 / 4);
    cvt_kernel<<<512, 256, 0, stream>>>(Wq, Wb,               1024 * 1024 / 4);
    cvt_kernel<<<512, 256, 0, stream>>>(Wk, Wb + 1024 * 1024, 1024 * 1024 / 4);
    cvt_kernel<<<512, 256, 0, stream>>>(Wv, Wb + 2 * 1024 * 1024, 1024 * 1024 / 4);

    gemm_qkv<<<dim3(64, 8, 3), 256, 0, stream>>>(xb, Wb, bq, bk, bv, QKV);

    attn_kernel<<<(BB * SS * NH) / 4, 256, 0, stream>>>(Qb, Kb, Vb, bk, bv, out);
}

// Round 2
// 122.839 us; speedup vs baseline: 2.4363x; 2.4363x over previous
//
#include <hip/hip_runtime.h>
#include <hip/hip_bf16.h>
#include <stdint.h>

typedef unsigned short ushort_t;
typedef __attribute__((ext_vector_type(8))) short bf16x8;   // 8 bf16 in 4 VGPRs
typedef __attribute__((ext_vector_type(4))) float f32x4;

#define BB 4
#define SS 2048
#define DD 1024
#define HDIM 1024
#define NH 16
#define DF 64
#define WWIN 16

__device__ __forceinline__ ushort_t f2bf(float f) {
    uint32_t u = __float_as_uint(f);
    u = (u + 0x7FFFu + ((u >> 16) & 1u)) >> 16;   // RNE
    return (ushort_t)u;
}
__device__ __forceinline__ float bf2f(ushort_t h) {
    return __uint_as_float(((uint32_t)h) << 16);
}

__device__ __forceinline__ void gld_lds16(const void* g, void* l) {
    __builtin_amdgcn_global_load_lds(
        (const __attribute__((address_space(1))) void*)g,
        (__attribute__((address_space(3))) void*)l, 16, 0, 0);
}

// ---------------- fp32 -> bf16 convert ----------------
__global__ void cvt_kernel(const float* __restrict__ src, ushort_t* __restrict__ dst, int n4) {
    int i = blockIdx.x * blockDim.x + threadIdx.x;
    int st = gridDim.x * blockDim.x;
    for (; i < n4; i += st) {
        float4 v = ((const float4*)src)[i];
        ushort4 o;
        o.x = f2bf(v.x); o.y = f2bf(v.y); o.z = f2bf(v.z); o.w = f2bf(v.w);
        ((ushort4*)dst)[i] = o;
    }
}

// convert the three 1024x1024 weight matrices in one launch (blockIdx.y picks src)
__global__ void cvt3_kernel(const float* __restrict__ s0, const float* __restrict__ s1,
                            const float* __restrict__ s2, ushort_t* __restrict__ dst, int n4) {
    const float* src = (blockIdx.y == 0) ? s0 : ((blockIdx.y == 1) ? s1 : s2);
    ushort_t* d = dst + (size_t)blockIdx.y * n4 * 4;
    int i = blockIdx.x * blockDim.x + threadIdx.x;
    int st = gridDim.x * blockDim.x;
    for (; i < n4; i += st) {
        float4 v = ((const float4*)src)[i];
        ushort4 o;
        o.x = f2bf(v.x); o.y = f2bf(v.y); o.z = f2bf(v.z); o.w = f2bf(v.w);
        ((ushort4*)d)[i] = o;
    }
}

// ---------------- fused QKV GEMM ----------------
__global__ __launch_bounds__(256) void gemm_qkv(
    const ushort_t* __restrict__ Aall,
    const ushort_t* __restrict__ Wall,
    const float* __restrict__ bq, const float* __restrict__ bk, const float* __restrict__ bv,
    ushort_t* __restrict__ Obase)
{
    const int z = blockIdx.z;
    const ushort_t* Bw = Wall + (size_t)z * 1024 * 1024;
    const float* bias = (z == 0) ? bq : ((z == 1) ? bk : bv);
    ushort_t* Out = Obase + (size_t)z * 8192 * 1024;

    const int m0 = blockIdx.x * 128;
    const int n0 = blockIdx.y * 128;
    const int K = 1024;

    __shared__ ushort_t As[128 * 32];
    __shared__ ushort_t Bs[128 * 32];

    const int t = threadIdx.x;
    const int wave = t >> 6, lane = t & 63;
    const int wm = wave >> 1, wn = wave & 1;       // 2x2 wave grid, 64x64 per wave
    const int frow = lane & 15;
    const int kcol = (lane >> 4) * 8;

    f32x4 acc[4][4] = {};

    for (int k0 = 0; k0 < K; k0 += 32) {
#pragma unroll
        for (int j = 0; j < 2; ++j) {
            int e = (j * 256 + t) * 8;             // element index in 128x32 tile
            int row = e >> 5, col = e & 31;
            gld_lds16(Aall + (size_t)(m0 + row) * K + k0 + col,
                      As + (size_t)(j * 256 + wave * 64) * 8);
            gld_lds16(Bw + (size_t)(n0 + row) * K + k0 + col,
                      Bs + (size_t)(j * 256 + wave * 64) * 8);
        }
        __syncthreads();

        bf16x8 af[4], bfr[4];
#pragma unroll
        for (int i = 0; i < 4; ++i) {
            af[i]  = *(const bf16x8*)(As + (wm * 64 + i * 16 + frow) * 32 + kcol);
            bfr[i] = *(const bf16x8*)(Bs + (wn * 64 + i * 16 + frow) * 32 + kcol);
        }
#pragma unroll
        for (int i = 0; i < 4; ++i)
#pragma unroll
            for (int j = 0; j < 4; ++j)
                acc[i][j] = __builtin_amdgcn_mfma_f32_16x16x32_bf16(af[i], bfr[j], acc[i][j], 0, 0, 0);
        __syncthreads();
    }

    const int orow0 = m0 + wm * 64;
    const int ocol0 = n0 + wn * 64;
#pragma unroll
    for (int j = 0; j < 4; ++j) {
        int col = ocol0 + j * 16 + frow;
        float bsv = bias[col];
#pragma unroll
        for (int i = 0; i < 4; ++i) {
#pragma unroll
            for (int rg = 0; rg < 4; ++rg) {
                int row = orow0 + i * 16 + (lane >> 4) * 4 + rg;
                Out[(size_t)row * 1024 + col] = f2bf(acc[i][j][rg] + bsv);
            }
        }
    }
}

// ---------------- attention (chunked-window softmax), quad-reduce layout ----
// wave per (b,s,h). lane l: window w = l>>2, d-slice = (l&3)*16 + [0,16)
__global__ __launch_bounds__(256) void attn_kernel(
    const ushort_t* __restrict__ Qb, const ushort_t* __restrict__ Kb, const ushort_t* __restrict__ Vb,
    const float* __restrict__ bk, const float* __restrict__ bv, float* __restrict__ out)
{
    const int wave = threadIdx.x >> 6, lane = threadIdx.x & 63;
    const int wg = blockIdx.x * 4 + wave;
    const int h = wg & 15;
    const int sb = wg >> 4;                // b*S + s
    const int s = sb & (SS - 1);
    const bool pad = (s + h < (WWIN - 1));
    const int dq = (lane & 3) << 4;        // d-slice start within the 64-chunk

    const size_t qbase = (size_t)sb * HDIM + h * DF;
    const size_t kbase = ((size_t)sb + h - (WWIN - 1)) * HDIM;  // row b*S + r (valid when !pad)

    // ---- QK^T partial dot (16 elems/lane) ----
    float p = 0.f;
    {
        const ushort_t* qp = Qb + qbase + dq;
        bf16x8 q0 = *(const bf16x8*)qp;
        bf16x8 q1 = *(const bf16x8*)(qp + 8);
        if (!pad) {
            const ushort_t* kp = Kb + kbase + ((size_t)lane << 4);   // contiguous 2KB/wave
            bf16x8 k0 = *(const bf16x8*)kp;
            bf16x8 k1 = *(const bf16x8*)(kp + 8);
#pragma unroll
            for (int j = 0; j < 8; ++j) {
                p += bf2f((ushort_t)q0[j]) * bf2f((ushort_t)k0[j]);
                p += bf2f((ushort_t)q1[j]) * bf2f((ushort_t)k1[j]);
            }
        } else {
            const float* kp = bk + (lane << 4);
#pragma unroll
            for (int j = 0; j < 8; ++j) {
                p += bf2f((ushort_t)q0[j]) * kp[j];
                p += bf2f((ushort_t)q1[j]) * kp[8 + j];
            }
        }
    }
    p *= 0.125f;                            // 1/sqrt(64)
    p += __shfl_xor(p, 1);
    p += __shfl_xor(p, 2);                  // lane now holds score[w], replicated in quad

    // ---- softmax across the 16 windows (strides 4..32) ----
    float m = p;
#pragma unroll
    for (int d = 4; d < 64; d <<= 1) m = fmaxf(m, __shfl_xor(m, d));
    float e = __expf(p - m);
    float sm = e;
#pragma unroll
    for (int d = 4; d < 64; d <<= 1) sm += __shfl_xor(sm, d);
    const float a = e / sm;

    // ---- PV: out[d=lane] = sum_w a[w] * v[w*64+lane] ----
    float acc = 0.f;
    if (!pad) {
        const ushort_t* vrow = Vb + kbase;
#pragma unroll
        for (int ww = 0; ww < 16; ++ww) {
            float aw = __shfl(a, ww << 2);
            acc += aw * bf2f(vrow[(ww << 6) + lane]);
        }
    } else {
#pragma unroll
        for (int ww = 0; ww < 16; ++ww) {
            float aw = __shfl(a, ww << 2);
            acc += aw * bv[(ww << 6) + lane];
        }
    }
    out[qbase + lane] = acc;
}

extern "C" void kernel_launch(void* const* d_in, const int* in_sizes, int n_in,
                              void* d_out, int out_size, void* d_ws, size_t ws_size,
                              hipStream_t stream) {
    const float* x  = (const float*)d_in[0];
    const float* Wq = (const float*)d_in[1];
    const float* bq = (const float*)d_in[2];
    const float* Wk = (const float*)d_in[3];
    const float* bk = (const float*)d_in[4];
    const float* Wv = (const float*)d_in[5];
    const float* bv = (const float*)d_in[6];
    float* out = (float*)d_out;

    ushort_t* xb  = (ushort_t*)d_ws;                       // 8192*1024 bf16
    ushort_t* Wb  = xb + (size_t)8192 * 1024;              // 3 * 1024*1024 bf16
    ushort_t* QKV = Wb + (size_t)3 * 1024 * 1024;          // 3 * 8192*1024 bf16
    ushort_t* Qb  = QKV;
    ushort_t* Kb  = QKV + (size_t)8192 * 1024;
    ushort_t* Vb  = QKV + (size_t)2 * 8192 * 1024;

    cvt_kernel<<<2048, 256, 0, stream>>>(x, xb, 8192 * 1024 / 4);
    cvt3_kernel<<<dim3(512, 3), 256, 0, stream>>>(Wq, Wk, Wv, Wb, 1024 * 1024 / 4);

    gemm_qkv<<<dim3(64, 8, 3), 256, 0, stream>>>(xb, Wb, bq, bk, bv, QKV);

    attn_kernel<<<(BB * SS * NH) / 4, 256, 0, stream>>>(Qb, Kb, Vb, bk, bv, out);
}

// Round 3
// 117.439 us; speedup vs baseline: 2.5483x; 1.0460x over previous
//
#include <hip/hip_runtime.h>
#include <hip/hip_bf16.h>
#include <stdint.h>

typedef unsigned short ushort_t;
typedef __attribute__((ext_vector_type(8))) short bf16x8;   // 8 bf16 in 4 VGPRs
typedef __attribute__((ext_vector_type(4))) float f32x4;

#define BB 4
#define SS 2048
#define HDIM 1024
#define NH 16
#define DF 64
#define WWIN 16

// ---- merged QKV GEMM config: C[8192,3072] = X[8192,1024] @ W[3072,1024]^T ----
#define GM 8192
#define GN 3072
#define GK 1024
#define BM 256
#define BN 128
#define BK 64
#define NT (GK / BK)                         // 16 K-tiles
#define LDS_TILE (BM * BK * 2 + BN * BK * 2) // 49152 B per buffer (A 32KB + B 16KB)
#define NBUF 3

__device__ __forceinline__ ushort_t f2bf(float f) {
    uint32_t u = __float_as_uint(f);
    u = (u + 0x7FFFu + ((u >> 16) & 1u)) >> 16;   // RNE
    return (ushort_t)u;
}
__device__ __forceinline__ float bf2f(ushort_t h) {
    return __uint_as_float(((uint32_t)h) << 16);
}

__device__ __forceinline__ void gld_lds16(const void* g, void* l) {
    __builtin_amdgcn_global_load_lds(
        (const __attribute__((address_space(1))) void*)g,
        (__attribute__((address_space(3))) void*)l, 16, 0, 0);
}

// ---------------- fp32 -> bf16 convert ----------------
__global__ void cvt_kernel(const float* __restrict__ src, ushort_t* __restrict__ dst, int n4) {
    int i = blockIdx.x * blockDim.x + threadIdx.x;
    int st = gridDim.x * blockDim.x;
    for (; i < n4; i += st) {
        float4 v = ((const float4*)src)[i];
        ushort4 o;
        o.x = f2bf(v.x); o.y = f2bf(v.y); o.z = f2bf(v.z); o.w = f2bf(v.w);
        ((ushort4*)dst)[i] = o;
    }
}

__global__ void cvt3_kernel(const float* __restrict__ s0, const float* __restrict__ s1,
                            const float* __restrict__ s2, ushort_t* __restrict__ dst, int n4) {
    const float* src = (blockIdx.y == 0) ? s0 : ((blockIdx.y == 1) ? s1 : s2);
    ushort_t* d = dst + (size_t)blockIdx.y * n4 * 4;
    int i = blockIdx.x * blockDim.x + threadIdx.x;
    int st = gridDim.x * blockDim.x;
    for (; i < n4; i += st) {
        float4 v = ((const float4*)src)[i];
        ushort4 o;
        o.x = f2bf(v.x); o.y = f2bf(v.y); o.z = f2bf(v.z); o.w = f2bf(v.w);
        ((ushort4*)d)[i] = o;
    }
}

// ---------------- deep-pipelined QKV GEMM ----------------
// 256x128 tile, BK=64, 8 waves (4M x 2N, 64x64 each), triple-buffered LDS,
// counted vmcnt(6), XOR-swizzled LDS (chunk ^= row&7 within 128B rows),
// operand-swapped MFMA for contiguous-column epilogue stores.
__global__ __launch_bounds__(512, 2) void gemm_qkv8(
    const ushort_t* __restrict__ Aall,   // [8192][1024] bf16
    const ushort_t* __restrict__ Wall,   // [3072][1024] bf16 (Wq|Wk|Wv)
    const float* __restrict__ bq, const float* __restrict__ bk, const float* __restrict__ bv,
    ushort_t* __restrict__ Obase)        // [3][8192][1024] bf16
{
    extern __shared__ char lds[];
    const int t = threadIdx.x;
    const int wave = t >> 6, lane = t & 63;
    const int wm = wave >> 1, wn = wave & 1;     // 4M x 2N wave grid
    const int frow = lane & 15, g = lane >> 4;
    const int sw = frow & 7;

    const int m0 = blockIdx.x * BM;
    const int nG0 = blockIdx.y * BN;             // global col in [0,3072)

    // stage one K-tile (A: 4 rounds, B: 2 rounds; 16B/lane, wave-uniform LDS base,
    // swizzle applied on the GLOBAL source side so LDS dest stays linear)
    auto STAGE = [&](int bufb, int kt) {
        const int kc = kt * BK;
        char* Lb = lds + bufb;
#pragma unroll
        for (int r = 0; r < 4; ++r) {
            int c = r * 512 + t;
            int row = c >> 3, slot = c & 7;
            gld_lds16(Aall + (size_t)(m0 + row) * GK + kc + ((slot ^ (row & 7)) << 3),
                      Lb + ((r * 512 + wave * 64) << 4));
        }
#pragma unroll
        for (int r = 0; r < 2; ++r) {
            int c = r * 512 + t;
            int row = c >> 3, slot = c & 7;
            gld_lds16(Wall + (size_t)(nG0 + row) * GK + kc + ((slot ^ (row & 7)) << 3),
                      Lb + 32768 + ((r * 512 + wave * 64) << 4));
        }
    };

    f32x4 acc[4][4] = {};

    STAGE(0, 0);
    STAGE(LDS_TILE, 1);
    asm volatile("s_waitcnt vmcnt(6)\ns_barrier" ::: "memory");

#pragma unroll
    for (int tt = 0; tt < NT; ++tt) {
        const int bb = (tt % 3) * LDS_TILE;
        const char* Ab = lds + bb;
        const char* Bb = lds + bb + 32768;

        if (tt + 2 < NT) STAGE(((tt + 2) % 3) * LDS_TILE, tt + 2);

#pragma unroll
        for (int kk = 0; kk < 2; ++kk) {
            bf16x8 af[4], bf[4];
#pragma unroll
            for (int i = 0; i < 4; ++i)
                af[i] = *(const bf16x8*)(Ab + ((wm * 64 + i * 16 + frow) << 7)
                                            + ((((kk << 2) + g) ^ sw) << 4));
#pragma unroll
            for (int j = 0; j < 4; ++j)
                bf[j] = *(const bf16x8*)(Bb + ((wn * 64 + j * 16 + frow) << 7)
                                            + ((((kk << 2) + g) ^ sw) << 4));
            __builtin_amdgcn_s_setprio(1);
#pragma unroll
            for (int i = 0; i < 4; ++i)
#pragma unroll
                for (int j = 0; j < 4; ++j)   // swapped operands: D^T fragments
                    acc[i][j] = __builtin_amdgcn_mfma_f32_16x16x32_bf16(bf[j], af[i], acc[i][j], 0, 0, 0);
            __builtin_amdgcn_s_setprio(0);
        }

        if (tt + 2 < NT) asm volatile("s_waitcnt vmcnt(6)\ns_barrier" ::: "memory");
        else             asm volatile("s_waitcnt vmcnt(0)\ns_barrier" ::: "memory");
    }

    // ---- epilogue: lane holds 4 consecutive cols (reg) at fixed row (lane&15) ----
    const int z = nG0 >> 10;                     // uniform per block (1024 % BN == 0)
    const float* bias = (z == 0) ? bq : ((z == 1) ? bk : bv);
    ushort_t* OutZ = Obase + (size_t)z * GM * 1024;
    const int n_base_in = (nG0 & 1023) + wn * 64;
    const int m_base = m0 + wm * 64;

#pragma unroll
    for (int i = 0; i < 4; ++i) {
        const size_t rowoff = (size_t)(m_base + i * 16 + frow) * 1024;
#pragma unroll
        for (int j = 0; j < 4; ++j) {
            const int nin = n_base_in + j * 16 + g * 4;
            float4 b4 = *(const float4*)(bias + nin);
            ushort4 o;
            o.x = f2bf(acc[i][j][0] + b4.x);
            o.y = f2bf(acc[i][j][1] + b4.y);
            o.z = f2bf(acc[i][j][2] + b4.z);
            o.w = f2bf(acc[i][j][3] + b4.w);
            *(ushort4*)(OutZ + rowoff + nin) = o;
        }
    }
}

// ---------------- attention (chunked-window softmax), quad-reduce layout ----
__global__ __launch_bounds__(256) void attn_kernel(
    const ushort_t* __restrict__ Qb, const ushort_t* __restrict__ Kb, const ushort_t* __restrict__ Vb,
    const float* __restrict__ bk, const float* __restrict__ bv, float* __restrict__ out)
{
    const int wave = threadIdx.x >> 6, lane = threadIdx.x & 63;
    const int wg = blockIdx.x * 4 + wave;
    const int h = wg & 15;
    const int sb = wg >> 4;                // b*S + s
    const int s = sb & (SS - 1);
    const bool pad = (s + h < (WWIN - 1));
    const int dq = (lane & 3) << 4;

    const size_t qbase = (size_t)sb * HDIM + h * DF;
    const size_t kbase = ((size_t)sb + h - (WWIN - 1)) * HDIM;

    float p = 0.f;
    {
        const ushort_t* qp = Qb + qbase + dq;
        bf16x8 q0 = *(const bf16x8*)qp;
        bf16x8 q1 = *(const bf16x8*)(qp + 8);
        if (!pad) {
            const ushort_t* kp = Kb + kbase + ((size_t)lane << 4);
            bf16x8 k0 = *(const bf16x8*)kp;
            bf16x8 k1 = *(const bf16x8*)(kp + 8);
#pragma unroll
            for (int j = 0; j < 8; ++j) {
                p += bf2f((ushort_t)q0[j]) * bf2f((ushort_t)k0[j]);
                p += bf2f((ushort_t)q1[j]) * bf2f((ushort_t)k1[j]);
            }
        } else {
            const float* kp = bk + (lane << 4);
#pragma unroll
            for (int j = 0; j < 8; ++j) {
                p += bf2f((ushort_t)q0[j]) * kp[j];
                p += bf2f((ushort_t)q1[j]) * kp[8 + j];
            }
        }
    }
    p *= 0.125f;
    p += __shfl_xor(p, 1);
    p += __shfl_xor(p, 2);

    float m = p;
#pragma unroll
    for (int d = 4; d < 64; d <<= 1) m = fmaxf(m, __shfl_xor(m, d));
    float e = __expf(p - m);
    float sm = e;
#pragma unroll
    for (int d = 4; d < 64; d <<= 1) sm += __shfl_xor(sm, d);
    const float a = e / sm;

    float acc = 0.f;
    if (!pad) {
        const ushort_t* vrow = Vb + kbase;
#pragma unroll
        for (int ww = 0; ww < 16; ++ww) {
            float aw = __shfl(a, ww << 2);
            acc += aw * bf2f(vrow[(ww << 6) + lane]);
        }
    } else {
#pragma unroll
        for (int ww = 0; ww < 16; ++ww) {
            float aw = __shfl(a, ww << 2);
            acc += aw * bv[(ww << 6) + lane];
        }
    }
    out[qbase + lane] = acc;
}

extern "C" void kernel_launch(void* const* d_in, const int* in_sizes, int n_in,
                              void* d_out, int out_size, void* d_ws, size_t ws_size,
                              hipStream_t stream) {
    const float* x  = (const float*)d_in[0];
    const float* Wq = (const float*)d_in[1];
    const float* bq = (const float*)d_in[2];
    const float* Wk = (const float*)d_in[3];
    const float* bk = (const float*)d_in[4];
    const float* Wv = (const float*)d_in[5];
    const float* bv = (const float*)d_in[6];
    float* out = (float*)d_out;

    ushort_t* xb  = (ushort_t*)d_ws;                       // 8192*1024 bf16
    ushort_t* Wb  = xb + (size_t)8192 * 1024;              // 3 * 1024*1024 bf16
    ushort_t* QKV = Wb + (size_t)3 * 1024 * 1024;          // 3 * 8192*1024 bf16
    ushort_t* Qb  = QKV;
    ushort_t* Kb  = QKV + (size_t)8192 * 1024;
    ushort_t* Vb  = QKV + (size_t)2 * 8192 * 1024;

    cvt_kernel<<<2048, 256, 0, stream>>>(x, xb, 8192 * 1024 / 4);
    cvt3_kernel<<<dim3(512, 3), 256, 0, stream>>>(Wq, Wk, Wv, Wb, 1024 * 1024 / 4);

    hipFuncSetAttribute(reinterpret_cast<const void*>(gemm_qkv8),
                        hipFuncAttributeMaxDynamicSharedMemorySize, NBUF * LDS_TILE);
    gemm_qkv8<<<dim3(GM / BM, GN / BN), 512, NBUF * LDS_TILE, stream>>>(
        xb, Wb, bq, bk, bv, QKV);

    attn_kernel<<<(BB * SS * NH) / 4, 256, 0, stream>>>(Qb, Kb, Vb, bk, bv, out);
}

// Round 4
// 115.261 us; speedup vs baseline: 2.5965x; 1.0189x over previous
//
#include <hip/hip_runtime.h>
#include <hip/hip_bf16.h>
#include <stdint.h>

typedef unsigned short ushort_t;
typedef __attribute__((ext_vector_type(8))) short bf16x8;   // 8 bf16 in 4 VGPRs
typedef __attribute__((ext_vector_type(4))) float f32x4;

#define BB 4
#define SS 2048
#define HDIM 1024
#define NH 16
#define DF 64
#define WWIN 16

// ---- merged QKV GEMM: C[8192,3072] = X[8192,1024] @ W[3072,1024]^T ----
#define GM 8192
#define GN 3072
#define GK 1024
#define BM 256
#define BN 192
#define BK 64
#define NT (GK / BK)                          // 16 K-tiles
#define ABYTES (BM * BK * 2)                  // 32768
#define LDS_TILE (BM * BK * 2 + BN * BK * 2)  // 57344 B per buffer
#define NBUF 2

__device__ __forceinline__ ushort_t f2bf(float f) {
    uint32_t u = __float_as_uint(f);
    u = (u + 0x7FFFu + ((u >> 16) & 1u)) >> 16;   // RNE
    return (ushort_t)u;
}
__device__ __forceinline__ float bf2f(ushort_t h) {
    return __uint_as_float(((uint32_t)h) << 16);
}

__device__ __forceinline__ void gld_lds16(const void* g, void* l) {
    __builtin_amdgcn_global_load_lds(
        (const __attribute__((address_space(1))) void*)g,
        (__attribute__((address_space(3))) void*)l, 16, 0, 0);
}

// ---------------- fp32 -> bf16 convert ----------------
__global__ void cvt_kernel(const float* __restrict__ src, ushort_t* __restrict__ dst, int n4) {
    int i = blockIdx.x * blockDim.x + threadIdx.x;
    int st = gridDim.x * blockDim.x;
    for (; i < n4; i += st) {
        float4 v = ((const float4*)src)[i];
        ushort4 o;
        o.x = f2bf(v.x); o.y = f2bf(v.y); o.z = f2bf(v.z); o.w = f2bf(v.w);
        ((ushort4*)dst)[i] = o;
    }
}

__global__ void cvt3_kernel(const float* __restrict__ s0, const float* __restrict__ s1,
                            const float* __restrict__ s2, ushort_t* __restrict__ dst, int n4) {
    const float* src = (blockIdx.y == 0) ? s0 : ((blockIdx.y == 1) ? s1 : s2);
    ushort_t* d = dst + (size_t)blockIdx.y * n4 * 4;
    int i = blockIdx.x * blockDim.x + threadIdx.x;
    int st = gridDim.x * blockDim.x;
    for (; i < n4; i += st) {
        float4 v = ((const float4*)src)[i];
        ushort4 o;
        o.x = f2bf(v.x); o.y = f2bf(v.y); o.z = f2bf(v.z); o.w = f2bf(v.w);
        ((ushort4*)d)[i] = o;
    }
}

// ---------------- QKV GEMM: 256x192 tile, per-wave 128x48 ----------------
// 8 waves (2M x 4N), BK=64, double-buffered LDS (2x56KB), issue-early staging,
// XOR-swizzled LDS chunks (chunk ^= row&7), operand-swapped MFMA epilogue,
// bijective XCD chunking (8 chunks of 8x8 tiles).
__global__ __launch_bounds__(512, 2) void gemm_qkv8(
    const ushort_t* __restrict__ Aall,   // [8192][1024] bf16
    const ushort_t* __restrict__ Wall,   // [3072][1024] bf16 (Wq|Wk|Wv)
    const float* __restrict__ bq, const float* __restrict__ bk, const float* __restrict__ bv,
    ushort_t* __restrict__ Obase)        // [3][8192][1024] bf16
{
    extern __shared__ char lds[];
    const int t = threadIdx.x;
    const int wave = t >> 6, lane = t & 63;
    const int wm = wave >> 2, wn = wave & 3;     // 2M x 4N wave grid -> 128x48 per wave
    const int frow = lane & 15, g = lane >> 4;
    const int sw = frow & 7;

    // XCD-chunked block decode: chunk = bid%8 -> (cm,cn); 8x8 tiles per chunk
    const int bid = blockIdx.x;
    const int cc = bid & 7, w = bid >> 3;
    const int bx = (cc & 3) * 8 + (w & 7);       // 0..31  (M tile)
    const int by = (cc >> 2) * 8 + (w >> 3);     // 0..15  (N tile)
    const int m0 = bx * BM;
    const int nG0 = by * BN;

    // stage one K-tile: A 4 rounds + B 3 rounds, 16B/lane, swizzle on global source
    auto STAGE = [&](int bufb, int kt) {
        const int kc = kt * BK;
        char* Lb = lds + bufb;
#pragma unroll
        for (int r = 0; r < 4; ++r) {
            int idx = r * 512 + t;
            int row = idx >> 3, slot = idx & 7;
            gld_lds16(Aall + (size_t)(m0 + row) * GK + kc + ((slot ^ (row & 7)) << 3),
                      Lb + ((r * 512 + wave * 64) << 4));
        }
#pragma unroll
        for (int r = 0; r < 3; ++r) {
            int idx = r * 512 + t;
            int row = idx >> 3, slot = idx & 7;
            gld_lds16(Wall + (size_t)(nG0 + row) * GK + kc + ((slot ^ (row & 7)) << 3),
                      Lb + ABYTES + ((r * 512 + wave * 64) << 4));
        }
    };

    f32x4 acc[8][3] = {};

    STAGE(0, 0);
    asm volatile("s_waitcnt vmcnt(0)\ns_barrier" ::: "memory");

#pragma unroll 2
    for (int tt = 0; tt < NT; ++tt) {
        // issue next tile's staging FIRST (full K-tile of compute covers latency)
        if (tt + 1 < NT) STAGE(((tt + 1) & 1) * LDS_TILE, tt + 1);

        const char* Ab = lds + (tt & 1) * LDS_TILE;
        const char* Bb = Ab + ABYTES;

#pragma unroll
        for (int kk = 0; kk < 2; ++kk) {
            bf16x8 af[8], bf[3];
#pragma unroll
            for (int i = 0; i < 8; ++i)
                af[i] = *(const bf16x8*)(Ab + ((wm * 128 + i * 16 + frow) << 7)
                                            + ((((kk << 2) + g) ^ sw) << 4));
#pragma unroll
            for (int j = 0; j < 3; ++j)
                bf[j] = *(const bf16x8*)(Bb + ((wn * 48 + j * 16 + frow) << 7)
                                            + ((((kk << 2) + g) ^ sw) << 4));
            __builtin_amdgcn_s_setprio(1);
#pragma unroll
            for (int i = 0; i < 8; ++i)
#pragma unroll
                for (int j = 0; j < 3; ++j)   // swapped operands: col-major D fragments
                    acc[i][j] = __builtin_amdgcn_mfma_f32_16x16x32_bf16(bf[j], af[i], acc[i][j], 0, 0, 0);
            __builtin_amdgcn_s_setprio(0);
        }

        if (tt + 1 < NT)
            asm volatile("s_waitcnt vmcnt(0)\ns_barrier" ::: "memory");
    }

    // ---- epilogue: lane holds 4 consecutive cols at fixed row (lane&15) ----
    const int m_base = m0 + wm * 128;
#pragma unroll
    for (int j = 0; j < 3; ++j) {
        const int colb = nG0 + wn * 48 + j * 16;   // 16-aligned -> single z per fragment
        const int z = colb >> 10;
        const int nin = (colb & 1023) + g * 4;
        const float* bias = (z == 0) ? bq : ((z == 1) ? bk : bv);
        ushort_t* OutZ = Obase + (size_t)z * GM * 1024;
        float4 b4 = *(const float4*)(bias + nin);
#pragma unroll
        for (int i = 0; i < 8; ++i) {
            const size_t rowoff = (size_t)(m_base + i * 16 + frow) * 1024;
            ushort4 o;
            o.x = f2bf(acc[i][j][0] + b4.x);
            o.y = f2bf(acc[i][j][1] + b4.y);
            o.z = f2bf(acc[i][j][2] + b4.z);
            o.w = f2bf(acc[i][j][3] + b4.w);
            *(ushort4*)(OutZ + rowoff + nin) = o;
        }
    }
}

// ---------------- attention (chunked-window softmax), quad-reduce layout ----
__global__ __launch_bounds__(256) void attn_kernel(
    const ushort_t* __restrict__ Qb, const ushort_t* __restrict__ Kb, const ushort_t* __restrict__ Vb,
    const float* __restrict__ bk, const float* __restrict__ bv, float* __restrict__ out)
{
    const int wave = threadIdx.x >> 6, lane = threadIdx.x & 63;
    const int wg = blockIdx.x * 4 + wave;
    const int h = wg & 15;
    const int sb = wg >> 4;                // b*S + s
    const int s = sb & (SS - 1);
    const bool pad = (s + h < (WWIN - 1));
    const int dq = (lane & 3) << 4;

    const size_t qbase = (size_t)sb * HDIM + h * DF;
    const size_t kbase = ((size_t)sb + h - (WWIN - 1)) * HDIM;

    float p = 0.f;
    {
        const ushort_t* qp = Qb + qbase + dq;
        bf16x8 q0 = *(const bf16x8*)qp;
        bf16x8 q1 = *(const bf16x8*)(qp + 8);
        if (!pad) {
            const ushort_t* kp = Kb + kbase + ((size_t)lane << 4);
            bf16x8 k0 = *(const bf16x8*)kp;
            bf16x8 k1 = *(const bf16x8*)(kp + 8);
#pragma unroll
            for (int j = 0; j < 8; ++j) {
                p += bf2f((ushort_t)q0[j]) * bf2f((ushort_t)k0[j]);
                p += bf2f((ushort_t)q1[j]) * bf2f((ushort_t)k1[j]);
            }
        } else {
            const float* kp = bk + (lane << 4);
#pragma unroll
            for (int j = 0; j < 8; ++j) {
                p += bf2f((ushort_t)q0[j]) * kp[j];
                p += bf2f((ushort_t)q1[j]) * kp[8 + j];
            }
        }
    }
    p *= 0.125f;
    p += __shfl_xor(p, 1);
    p += __shfl_xor(p, 2);

    float m = p;
#pragma unroll
    for (int d = 4; d < 64; d <<= 1) m = fmaxf(m, __shfl_xor(m, d));
    float e = __expf(p - m);
    float sm = e;
#pragma unroll
    for (int d = 4; d < 64; d <<= 1) sm += __shfl_xor(sm, d);
    const float a = e / sm;

    float acc = 0.f;
    if (!pad) {
        const ushort_t* vrow = Vb + kbase;
#pragma unroll
        for (int ww = 0; ww < 16; ++ww) {
            float aw = __shfl(a, ww << 2);
            acc += aw * bf2f(vrow[(ww << 6) + lane]);
        }
    } else {
#pragma unroll
        for (int ww = 0; ww < 16; ++ww) {
            float aw = __shfl(a, ww << 2);
            acc += aw * bv[(ww << 6) + lane];
        }
    }
    out[qbase + lane] = acc;
}

extern "C" void kernel_launch(void* const* d_in, const int* in_sizes, int n_in,
                              void* d_out, int out_size, void* d_ws, size_t ws_size,
                              hipStream_t stream) {
    const float* x  = (const float*)d_in[0];
    const float* Wq = (const float*)d_in[1];
    const float* bq = (const float*)d_in[2];
    const float* Wk = (const float*)d_in[3];
    const float* bk = (const float*)d_in[4];
    const float* Wv = (const float*)d_in[5];
    const float* bv = (const float*)d_in[6];
    float* out = (float*)d_out;

    ushort_t* xb  = (ushort_t*)d_ws;                       // 8192*1024 bf16
    ushort_t* Wb  = xb + (size_t)8192 * 1024;              // 3 * 1024*1024 bf16
    ushort_t* QKV = Wb + (size_t)3 * 1024 * 1024;          // 3 * 8192*1024 bf16
    ushort_t* Qb  = QKV;
    ushort_t* Kb  = QKV + (size_t)8192 * 1024;
    ushort_t* Vb  = QKV + (size_t)2 * 8192 * 1024;

    cvt_kernel<<<2048, 256, 0, stream>>>(x, xb, 8192 * 1024 / 4);
    cvt3_kernel<<<dim3(512, 3), 256, 0, stream>>>(Wq, Wk, Wv, Wb, 1024 * 1024 / 4);

    hipFuncSetAttribute(reinterpret_cast<const void*>(gemm_qkv8),
                        hipFuncAttributeMaxDynamicSharedMemorySize, NBUF * LDS_TILE);
    gemm_qkv8<<<dim3((GM / BM) * (GN / BN)), 512, NBUF * LDS_TILE, stream>>>(
        xb, Wb, bq, bk, bv, QKV);

    attn_kernel<<<(BB * SS * NH) / 4, 256, 0, stream>>>(Qb, Kb, Vb, bk, bv, out);
}